// Round 8
// baseline (259.951 us; speedup 1.0000x reference)
//
#include <hip/hip_runtime.h>
#include <hip/hip_bf16.h>
#include <hip/hip_cooperative_groups.h>
#include <stdint.h>

namespace cg = cooperative_groups;

// DiffLogic: 3-layer differentiable logic network.
// Round 8: single cooperative kernel. Phases: coef+transpose+zero ->
// grid.sync -> layer1 -> sync -> layer2 -> sync -> layer3+reduce.
// 256 blocks x 1024 threads (co-resident by construction), bf16 activations,
// R6's proven ushort4 gather inner loop.

#define BATCH   256
#define IN_DIM  1024
#define WIDTH   64000
#define NGROUP  10
#define GSIZE   6400
#define TAU     30.0f
#define NBLK    256
#define NTHR    1024
#define NWAVE   16                    // waves per block
#define NWAVES_G (NBLK*NWAVE)         // 4096 global waves
#define CHSZ    8                     // gates per chunk
#define NCHUNK  (WIDTH/CHSZ)          // 8000

typedef unsigned short ushort_t;

static __device__ __forceinline__ float bf2f(ushort_t s) {
    return __uint_as_float((uint32_t)s << 16);
}
static __device__ __forceinline__ ushort_t f2bf(float f) {   // RNE
    uint32_t u = __float_as_uint(f);
    return (ushort_t)((u + 0x7fffu + ((u >> 16) & 1u)) >> 16);
}

// ---- per-gate math --------------------------------------------------------
static __device__ __forceinline__ float4 gate4(float4 c, ushort4 a4, ushort4 b4) {
    const float Ax = bf2f(a4.x), Ay = bf2f(a4.y), Az = bf2f(a4.z), Aw = bf2f(a4.w);
    const float Bx = bf2f(b4.x), By = bf2f(b4.y), Bz = bf2f(b4.z), Bw = bf2f(b4.w);
    float4 r;
    r.x = fmaf(c.w, Ax * Bx, fmaf(c.z, Bx, fmaf(c.y, Ax, c.x)));
    r.y = fmaf(c.w, Ay * By, fmaf(c.z, By, fmaf(c.y, Ay, c.x)));
    r.z = fmaf(c.w, Az * Bz, fmaf(c.z, Bz, fmaf(c.y, Az, c.x)));
    r.w = fmaf(c.w, Aw * Bw, fmaf(c.z, Bw, fmaf(c.y, Aw, c.x)));
    return r;
}

// ---- non-final layer pass: grid-strided 8-gate chunks ---------------------
static __device__ __forceinline__ void layer_pass(
    const ushort_t* __restrict__ in, const float4* __restrict__ coefs,
    const int* __restrict__ ia, const int* __restrict__ ib,
    ushort_t* __restrict__ outp, int lane, int gwave)
{
    for (int ch = gwave; ch < NCHUNK; ch += NWAVES_G) {
        const int jw = ch * CHSZ;
        int av[CHSZ], bv[CHSZ];
        #pragma unroll
        for (int u = 0; u < CHSZ; ++u) { av[u] = ia[jw + u]; bv[u] = ib[jw + u]; }
        #pragma unroll
        for (int u = 0; u < CHSZ; ++u) {
            const float4 c = coefs[jw + u];
            const ushort4 a4 = ((const ushort4*)(in + (size_t)av[u] * BATCH))[lane];
            const ushort4 b4 = ((const ushort4*)(in + (size_t)bv[u] * BATCH))[lane];
            const float4 r = gate4(c, a4, b4);
            ushort4 o;
            o.x = f2bf(r.x); o.y = f2bf(r.y); o.z = f2bf(r.z); o.w = f2bf(r.w);
            ((ushort4*)(outp + (size_t)(jw + u) * BATCH))[lane] = o;
        }
    }
}

// ---- fused kernel ---------------------------------------------------------
__global__ __launch_bounds__(NTHR, 4) void fused_kernel(
    const float* __restrict__ x,
    const float* __restrict__ w1, const float* __restrict__ w2,
    const float* __restrict__ w3,
    const int* __restrict__ ia1, const int* __restrict__ ib1,
    const int* __restrict__ ia2, const int* __restrict__ ib2,
    const int* __restrict__ ia3, const int* __restrict__ ib3,
    ushort_t* __restrict__ xT, ushort_t* __restrict__ h1,
    ushort_t* __restrict__ h2,
    float4* __restrict__ c1, float4* __restrict__ c2, float4* __restrict__ c3,
    float* __restrict__ out)
{
    cg::grid_group grid = cg::this_grid();
    const int lane = threadIdx.x & 63;
    const int wave = __builtin_amdgcn_readfirstlane((int)(threadIdx.x >> 6));
    const int blk  = blockIdx.x;
    const int tid  = blk * NTHR + threadIdx.x;     // 0 .. 262143
    const int gwave = blk * NWAVE + wave;          // 0 .. 4095

    // ---- phase 0a: gate coefficients (192000 gates, one thread each) ----
    if (tid < 3 * WIDTH) {
        const int layer = tid / WIDTH;
        const int j = tid - layer * WIDTH;
        const float* w = (layer == 0) ? w1 : (layer == 1) ? w2 : w3;
        float4* cc     = (layer == 0) ? c1 : (layer == 1) ? c2 : c3;
        const float4* w4 = (const float4*)(w + (size_t)j * 16);
        float4 q0 = w4[0], q1 = w4[1], q2 = w4[2], q3 = w4[3];
        float p[16] = {q0.x,q0.y,q0.z,q0.w, q1.x,q1.y,q1.z,q1.w,
                       q2.x,q2.y,q2.z,q2.w, q3.x,q3.y,q3.z,q3.w};
        float m = p[0];
        #pragma unroll
        for (int i = 1; i < 16; ++i) m = fmaxf(m, p[i]);
        float s = 0.f;
        #pragma unroll
        for (int i = 0; i < 16; ++i) { p[i] = __expf(p[i] - m); s += p[i]; }
        const float inv = 1.0f / s;
        float g0 = (p[8]+p[9]+p[10]+p[11]+p[12]+p[13]+p[14]+p[15]) * inv;
        float g1 = (p[2]+p[3]+p[6]+p[7] - p[8]-p[9]-p[12]-p[13]) * inv;
        float g2 = (p[4]+p[5]+p[6]+p[7] - p[8]-p[9]-p[10]-p[11]) * inv;
        float g3 = (p[1]-p[2]-p[4]-2.f*p[6]-p[7]+p[8]+2.f*p[9]+p[11]+p[13]-p[14]) * inv;
        cc[j] = make_float4(g0, g1, g2, g3);
    }

    // ---- phase 0b: transpose x (256,1024) f32 -> xT (1024,256) bf16 ----
    {   // 262144 elements == grid threads; coalesced bf16 write
        const int c = tid >> 8;
        const int b = tid & 255;
        xT[tid] = f2bf(x[b * IN_DIM + c]);
    }

    // ---- phase 0c: zero output ----
    if (tid < BATCH * NGROUP) out[tid] = 0.f;

    grid.sync();

    // ---- layer 1: xT -> h1 ----
    layer_pass(xT, c1, ia1, ib1, h1, lane, gwave);
    grid.sync();

    // ---- layer 2: h1 -> h2 ----
    layer_pass(h1, c2, ia2, ib2, h2, lane, gwave);
    grid.sync();

    // ---- layer 3 + group reduction ----
    // blocks 0..249: 256 contiguous gates each (within one group; 6400%256==0)
    __shared__ float4 s[NWAVE][64];
    float4 acc = make_float4(0.f, 0.f, 0.f, 0.f);
    if (blk < 250) {
        #pragma unroll
        for (int k = 0; k < 2; ++k) {
            const int jw = (blk * 32 + wave * 2 + k) * CHSZ;
            int av[CHSZ], bv[CHSZ];
            #pragma unroll
            for (int u = 0; u < CHSZ; ++u) { av[u] = ia3[jw + u]; bv[u] = ib3[jw + u]; }
            #pragma unroll
            for (int u = 0; u < CHSZ; ++u) {
                const float4 c = c3[jw + u];
                const ushort4 a4 = ((const ushort4*)(h2 + (size_t)av[u] * BATCH))[lane];
                const ushort4 b4 = ((const ushort4*)(h2 + (size_t)bv[u] * BATCH))[lane];
                const float4 r = gate4(c, a4, b4);
                acc.x += r.x; acc.y += r.y; acc.z += r.z; acc.w += r.w;
            }
        }
    }
    s[wave][lane] = acc;
    __syncthreads();
    if (wave == 0 && blk < 250) {
        float4 t = s[0][lane];
        #pragma unroll
        for (int w = 1; w < NWAVE; ++w) {
            float4 q = s[w][lane];
            t.x += q.x; t.y += q.y; t.z += q.z; t.w += q.w;
        }
        const float sc = 1.0f / TAU;
        const int grp = (blk * 256) / GSIZE;
        const int b0 = lane * 4;
        atomicAdd(&out[(b0 + 0) * NGROUP + grp], t.x * sc);
        atomicAdd(&out[(b0 + 1) * NGROUP + grp], t.y * sc);
        atomicAdd(&out[(b0 + 2) * NGROUP + grp], t.z * sc);
        atomicAdd(&out[(b0 + 3) * NGROUP + grp], t.w * sc);
    }
}

// ---------------------------------------------------------------- launch
extern "C" void kernel_launch(void* const* d_in, const int* in_sizes, int n_in,
                              void* d_out, int out_size, void* d_ws, size_t ws_size,
                              hipStream_t stream)
{
    const float* x   = (const float*)d_in[0];
    const float* w1  = (const float*)d_in[1];
    const float* w2  = (const float*)d_in[2];
    const float* w3  = (const float*)d_in[3];
    const int*   ia1 = (const int*)d_in[4];
    const int*   ib1 = (const int*)d_in[5];
    const int*   ia2 = (const int*)d_in[6];
    const int*   ib2 = (const int*)d_in[7];
    const int*   ia3 = (const int*)d_in[8];
    const int*   ib3 = (const int*)d_in[9];
    float* out = (float*)d_out;

    // workspace: xT | h1 | h2 | c1 | c2 | c3 (~69 MB, 16B-aligned segments)
    char* ws = (char*)d_ws;
    ushort_t* xT = (ushort_t*)ws;
    ushort_t* h1 = (ushort_t*)(ws + ((size_t)IN_DIM * BATCH * 2));
    ushort_t* h2 = h1 + (size_t)WIDTH * BATCH;
    float*    c1 = (float*)(h2 + (size_t)WIDTH * BATCH);
    float*    c2 = c1 + (size_t)WIDTH * 4;
    float*    c3 = c2 + (size_t)WIDTH * 4;

    void* args[] = {
        (void*)&x, (void*)&w1, (void*)&w2, (void*)&w3,
        (void*)&ia1, (void*)&ib1, (void*)&ia2, (void*)&ib2,
        (void*)&ia3, (void*)&ib3,
        (void*)&xT, (void*)&h1, (void*)&h2,
        (void*)&c1, (void*)&c2, (void*)&c3,
        (void*)&out
    };
    hipLaunchCooperativeKernel((void*)fused_kernel, dim3(NBLK), dim3(NTHR),
                               args, 0, stream);
}

// Round 9
// 160.461 us; speedup vs baseline: 1.6200x; 1.6200x over previous
//
#include <hip/hip_runtime.h>
#include <hip/hip_bf16.h>
#include <stdint.h>

// DiffLogic: 3-layer differentiable logic network.
// Round 9: multi-dispatch (R6 shape) + ONE asm block per wave holding all 16
// column gathers and the waitcnt -> compiler cannot sink/serialize; 16 loads
// in flight per wave (vs ~2 in R1-R8). 1000 blocks x 512 thr, 32 waves/CU.

#define BATCH   256
#define IN_DIM  1024
#define WIDTH   64000
#define NGROUP  10
#define GSIZE   6400
#define TAU     30.0f
#define GPW     8                 // gates per wave
#define WPB     8                 // waves per block (512 thr)
#define GPB     (GPW*WPB)         // 64 gates/block; 6400 % 64 == 0
#define NBLK    (WIDTH/GPB)       // 1000

typedef unsigned short ushort_t;

static __device__ __forceinline__ float bfbits(uint32_t hi16) {
    return __uint_as_float(hi16 << 16);
}
static __device__ __forceinline__ ushort_t f2bf(float f) {   // RNE
    uint32_t u = __float_as_uint(f);
    return (ushort_t)((u + 0x7fffu + ((u >> 16) & 1u)) >> 16);
}

// ---------------------------------------------------------------- transpose
// x:(256,1024) f32 row-major -> xT:(1024,256) bf16
__global__ __launch_bounds__(256) void transpose_kernel(
    const float* __restrict__ x, ushort_t* __restrict__ xT)
{
    __shared__ float tile[64][65];
    const int c0 = (blockIdx.x & 15) * 64;
    const int b0 = (blockIdx.x >> 4) * 64;
    const int lt = threadIdx.x & 63;
    const int wt = threadIdx.x >> 6;
    for (int r = wt; r < 64; r += 4)
        tile[r][lt] = x[(b0 + r) * IN_DIM + c0 + lt];
    __syncthreads();
    for (int r = wt; r < 64; r += 4)
        xT[(c0 + r) * BATCH + b0 + lt] = f2bf(tile[lt][r]);
}

// ---------------------------------------------------------------- coefficients
__global__ __launch_bounds__(256) void coef_kernel(
    const float* __restrict__ w1, const float* __restrict__ w2,
    const float* __restrict__ w3,
    float4* __restrict__ c1o, float4* __restrict__ c2o, float4* __restrict__ c3o)
{
    const int id = blockIdx.x * 256 + threadIdx.x;
    const int layer = id / WIDTH;
    const int j = id - layer * WIDTH;
    const float* w = (layer == 0) ? w1 : (layer == 1) ? w2 : w3;
    float4* cc     = (layer == 0) ? c1o : (layer == 1) ? c2o : c3o;

    const float4* w4 = (const float4*)(w + (size_t)j * 16);
    float4 q0 = w4[0], q1 = w4[1], q2 = w4[2], q3 = w4[3];
    float p[16] = {q0.x,q0.y,q0.z,q0.w, q1.x,q1.y,q1.z,q1.w,
                   q2.x,q2.y,q2.z,q2.w, q3.x,q3.y,q3.z,q3.w};
    float m = p[0];
    #pragma unroll
    for (int i = 1; i < 16; ++i) m = fmaxf(m, p[i]);
    float s = 0.f;
    #pragma unroll
    for (int i = 0; i < 16; ++i) { p[i] = __expf(p[i] - m); s += p[i]; }
    const float inv = 1.0f / s;

    float c0 = (p[8]+p[9]+p[10]+p[11]+p[12]+p[13]+p[14]+p[15]) * inv;
    float c1 = (p[2]+p[3]+p[6]+p[7] - p[8]-p[9]-p[12]-p[13]) * inv;
    float c2 = (p[4]+p[5]+p[6]+p[7] - p[8]-p[9]-p[10]-p[11]) * inv;
    float c3 = (p[1]-p[2]-p[4]-2.f*p[6]-p[7]+p[8]+2.f*p[9]+p[11]+p[13]-p[14]) * inv;
    cc[j] = make_float4(c0, c1, c2, c3);
}

// ---------------------------------------------------------------- logic layer
// in : (in_width, 256) bf16 columns; column = 512 B; lane slice = 8 B.
// All 16 gathers + waitcnt live in ONE asm volatile block (tied "+v" ops:
// address in, data out) -> guaranteed 16 outstanding loads per wave.
template<bool FINAL>
__global__ __launch_bounds__(512, 8) void logic_layer_kernel(
    const ushort_t* __restrict__ in,
    const float4*   __restrict__ coefs,
    const int*      __restrict__ ia,
    const int*      __restrict__ ib,
    ushort_t*       __restrict__ out,
    float*          __restrict__ red_out)
{
    const int lane = threadIdx.x & 63;
    const int wave = __builtin_amdgcn_readfirstlane((int)(threadIdx.x >> 6));
    const int jw = blockIdx.x * GPB + wave * GPW;   // wave's 8 contiguous gates

    int av[GPW], bv[GPW];
    #pragma unroll
    for (int u = 0; u < GPW; ++u) { av[u] = ia[jw + u]; bv[u] = ib[jw + u]; }

    const char* base = (const char*)in;
    const int loff = lane << 3;                     // 8 B per lane
    uint64_t A[GPW], B[GPW];
    #pragma unroll
    for (int u = 0; u < GPW; ++u) {
        A[u] = (uint64_t)(base + (((size_t)(uint32_t)av[u]) << 9) + loff);
        B[u] = (uint64_t)(base + (((size_t)(uint32_t)bv[u]) << 9) + loff);
    }

    asm volatile(
        "global_load_dwordx2 %0, %0, off\n\t"
        "global_load_dwordx2 %1, %1, off\n\t"
        "global_load_dwordx2 %2, %2, off\n\t"
        "global_load_dwordx2 %3, %3, off\n\t"
        "global_load_dwordx2 %4, %4, off\n\t"
        "global_load_dwordx2 %5, %5, off\n\t"
        "global_load_dwordx2 %6, %6, off\n\t"
        "global_load_dwordx2 %7, %7, off\n\t"
        "global_load_dwordx2 %8, %8, off\n\t"
        "global_load_dwordx2 %9, %9, off\n\t"
        "global_load_dwordx2 %10, %10, off\n\t"
        "global_load_dwordx2 %11, %11, off\n\t"
        "global_load_dwordx2 %12, %12, off\n\t"
        "global_load_dwordx2 %13, %13, off\n\t"
        "global_load_dwordx2 %14, %14, off\n\t"
        "global_load_dwordx2 %15, %15, off\n\t"
        "s_waitcnt vmcnt(0)"
        : "+v"(A[0]), "+v"(B[0]), "+v"(A[1]), "+v"(B[1]),
          "+v"(A[2]), "+v"(B[2]), "+v"(A[3]), "+v"(B[3]),
          "+v"(A[4]), "+v"(B[4]), "+v"(A[5]), "+v"(B[5]),
          "+v"(A[6]), "+v"(B[6]), "+v"(A[7]), "+v"(B[7])
        :
        : "memory");

    float4 acc = make_float4(0.f, 0.f, 0.f, 0.f);
    #pragma unroll
    for (int u = 0; u < GPW; ++u) {
        const float4 c = coefs[jw + u];
        const uint64_t a = A[u], b = B[u];
        const float Ax = bfbits((uint32_t)a & 0xffffu);
        const float Ay = bfbits(((uint32_t)a >> 16) & 0xffffu);
        const float Az = bfbits((uint32_t)(a >> 32) & 0xffffu);
        const float Aw = bfbits((uint32_t)(a >> 48));
        const float Bx = bfbits((uint32_t)b & 0xffffu);
        const float By = bfbits(((uint32_t)b >> 16) & 0xffffu);
        const float Bz = bfbits((uint32_t)(b >> 32) & 0xffffu);
        const float Bw = bfbits((uint32_t)(b >> 48));
        float4 r;
        r.x = fmaf(c.w, Ax * Bx, fmaf(c.z, Bx, fmaf(c.y, Ax, c.x)));
        r.y = fmaf(c.w, Ay * By, fmaf(c.z, By, fmaf(c.y, Ay, c.x)));
        r.z = fmaf(c.w, Az * Bz, fmaf(c.z, Bz, fmaf(c.y, Az, c.x)));
        r.w = fmaf(c.w, Aw * Bw, fmaf(c.z, Bw, fmaf(c.y, Aw, c.x)));
        if (FINAL) {
            acc.x += r.x; acc.y += r.y; acc.z += r.z; acc.w += r.w;
        } else {
            ushort4 o;
            o.x = f2bf(r.x); o.y = f2bf(r.y); o.z = f2bf(r.z); o.w = f2bf(r.w);
            ((ushort4*)(out + (size_t)(jw + u) * BATCH))[lane] = o;
        }
    }

    if (FINAL) {
        __shared__ float4 s[WPB][64];     // 8 KB
        s[wave][lane] = acc;
        __syncthreads();
        if (wave == 0) {
            float4 t = s[0][lane];
            #pragma unroll
            for (int w = 1; w < WPB; ++w) {
                float4 q = s[w][lane];
                t.x += q.x; t.y += q.y; t.z += q.z; t.w += q.w;
            }
            const float sc = 1.0f / TAU;
            const int grp = (blockIdx.x * GPB) / GSIZE;   // block within one group
            const int b0 = lane * 4;
            atomicAdd(&red_out[(b0 + 0) * NGROUP + grp], t.x * sc);
            atomicAdd(&red_out[(b0 + 1) * NGROUP + grp], t.y * sc);
            atomicAdd(&red_out[(b0 + 2) * NGROUP + grp], t.z * sc);
            atomicAdd(&red_out[(b0 + 3) * NGROUP + grp], t.w * sc);
        }
    }
}

// ---------------------------------------------------------------- launch
extern "C" void kernel_launch(void* const* d_in, const int* in_sizes, int n_in,
                              void* d_out, int out_size, void* d_ws, size_t ws_size,
                              hipStream_t stream)
{
    const float* x   = (const float*)d_in[0];
    const float* w1  = (const float*)d_in[1];
    const float* w2  = (const float*)d_in[2];
    const float* w3  = (const float*)d_in[3];
    const int*   ia1 = (const int*)d_in[4];
    const int*   ib1 = (const int*)d_in[5];
    const int*   ia2 = (const int*)d_in[6];
    const int*   ib2 = (const int*)d_in[7];
    const int*   ia3 = (const int*)d_in[8];
    const int*   ib3 = (const int*)d_in[9];
    float* out = (float*)d_out;

    // workspace: xT | h1 | h2 | c1 | c2 | c3 (~69 MB, 16B-aligned segments)
    char* ws = (char*)d_ws;
    ushort_t* xT = (ushort_t*)ws;
    ushort_t* h1 = (ushort_t*)(ws + ((size_t)IN_DIM * BATCH * 2));
    ushort_t* h2 = h1 + (size_t)WIDTH * BATCH;
    float*    c1 = (float*)(h2 + (size_t)WIDTH * BATCH);
    float*    c2 = c1 + (size_t)WIDTH * 4;
    float*    c3 = c2 + (size_t)WIDTH * 4;

    hipMemsetAsync(d_out, 0, (size_t)out_size * sizeof(float), stream);

    transpose_kernel<<<64, 256, 0, stream>>>(x, xT);
    coef_kernel<<<(3 * WIDTH) / 256, 256, 0, stream>>>(w1, w2, w3,
                                                       (float4*)c1, (float4*)c2, (float4*)c3);

    logic_layer_kernel<false><<<NBLK, 512, 0, stream>>>(
        xT, (const float4*)c1, ia1, ib1, h1, nullptr);
    logic_layer_kernel<false><<<NBLK, 512, 0, stream>>>(
        h1, (const float4*)c2, ia2, ib2, h2, nullptr);
    logic_layer_kernel<true><<<NBLK, 512, 0, stream>>>(
        h2, (const float4*)c3, ia3, ib3, nullptr, out);
}

// Round 10
// 145.088 us; speedup vs baseline: 1.7917x; 1.1060x over previous
//
#include <hip/hip_runtime.h>
#include <hip/hip_bf16.h>
#include <stdint.h>

// DiffLogic: 3-layer differentiable logic network.
// Round 10: split-wave packed gathers. One dwordx4 request (16 B/lane)
// fetches TWO bf16 columns: lanes 0-31 -> gate j, lanes 32-63 -> gate j+1.
// Halves wave-level request count (the unit that has predicted time in all
// 9 rounds). Shape: proven 500 blocks x 1024 threads.

#define BATCH   256
#define IN_DIM  1024
#define WIDTH   64000
#define NGROUP  10
#define GSIZE   6400
#define TAU     30.0f
#define NWAVE   16                // waves per block
#define GPW     8                 // gates per wave (4 pairs)
#define GPB     (NWAVE*GPW)       // 128; 6400 % 128 == 0
#define NBLK    (WIDTH/GPB)       // 500

typedef unsigned short ushort_t;

static __device__ __forceinline__ float bfbits(uint32_t hi16) {
    return __uint_as_float(hi16 << 16);
}
static __device__ __forceinline__ uint32_t f2bf_u(float f) {   // RNE
    uint32_t u = __float_as_uint(f);
    return (u + 0x7fffu + ((u >> 16) & 1u)) >> 16;
}

// ---------------------------------------------------------------- transpose
// x:(256,1024) f32 row-major -> xT:(1024,256) bf16
__global__ __launch_bounds__(256) void transpose_kernel(
    const float* __restrict__ x, ushort_t* __restrict__ xT)
{
    __shared__ float tile[64][65];
    const int c0 = (blockIdx.x & 15) * 64;
    const int b0 = (blockIdx.x >> 4) * 64;
    const int lt = threadIdx.x & 63;
    const int wt = threadIdx.x >> 6;
    for (int r = wt; r < 64; r += 4)
        tile[r][lt] = x[(b0 + r) * IN_DIM + c0 + lt];
    __syncthreads();
    for (int r = wt; r < 64; r += 4)
        xT[(c0 + r) * BATCH + b0 + lt] = (ushort_t)f2bf_u(tile[lt][r]);
}

// ---------------------------------------------------------------- coefficients
__global__ __launch_bounds__(256) void coef_kernel(
    const float* __restrict__ w1, const float* __restrict__ w2,
    const float* __restrict__ w3,
    float4* __restrict__ c1o, float4* __restrict__ c2o, float4* __restrict__ c3o)
{
    const int id = blockIdx.x * 256 + threadIdx.x;
    const int layer = id / WIDTH;
    const int j = id - layer * WIDTH;
    const float* w = (layer == 0) ? w1 : (layer == 1) ? w2 : w3;
    float4* cc     = (layer == 0) ? c1o : (layer == 1) ? c2o : c3o;

    const float4* w4 = (const float4*)(w + (size_t)j * 16);
    float4 q0 = w4[0], q1 = w4[1], q2 = w4[2], q3 = w4[3];
    float p[16] = {q0.x,q0.y,q0.z,q0.w, q1.x,q1.y,q1.z,q1.w,
                   q2.x,q2.y,q2.z,q2.w, q3.x,q3.y,q3.z,q3.w};
    float m = p[0];
    #pragma unroll
    for (int i = 1; i < 16; ++i) m = fmaxf(m, p[i]);
    float s = 0.f;
    #pragma unroll
    for (int i = 0; i < 16; ++i) { p[i] = __expf(p[i] - m); s += p[i]; }
    const float inv = 1.0f / s;

    float c0 = (p[8]+p[9]+p[10]+p[11]+p[12]+p[13]+p[14]+p[15]) * inv;
    float c1 = (p[2]+p[3]+p[6]+p[7] - p[8]-p[9]-p[12]-p[13]) * inv;
    float c2 = (p[4]+p[5]+p[6]+p[7] - p[8]-p[9]-p[10]-p[11]) * inv;
    float c3 = (p[1]-p[2]-p[4]-2.f*p[6]-p[7]+p[8]+2.f*p[9]+p[11]+p[13]-p[14]) * inv;
    cc[j] = make_float4(c0, c1, c2, c3);
}

// ---------------------------------------------------------------- logic layer
// in : (in_width, 256) bf16 columns (512 B each).
// Pairing: lanes 0-31 process gate 2p, lanes 32-63 gate 2p+1; each lane holds
// 16 B = 8 bf16 batch elems [l32*8 .. l32*8+8).
template<bool FINAL>
__global__ __launch_bounds__(1024) void logic_layer_kernel(
    const ushort_t* __restrict__ in,
    const float4*   __restrict__ coefs,
    const int*      __restrict__ ia,
    const int*      __restrict__ ib,
    ushort_t*       __restrict__ out,
    float*          __restrict__ red_out)
{
    const int lane = threadIdx.x & 63;
    const int wave = __builtin_amdgcn_readfirstlane((int)(threadIdx.x >> 6));
    const int half = lane >> 5;            // 0: even gate, 1: odd gate
    const int l32  = lane & 31;
    const int jw = blockIdx.x * GPB + wave * GPW;

    int av[GPW], bv[GPW];
    #pragma unroll
    for (int u = 0; u < GPW; ++u) { av[u] = ia[jw + u]; bv[u] = ib[jw + u]; }

    const char* base = (const char*)in;
    const int lo16 = l32 << 4;             // 16 B per lane within column

    float acc[8];
    #pragma unroll
    for (int i = 0; i < 8; ++i) acc[i] = 0.f;

    #pragma unroll
    for (int p = 0; p < GPW / 2; ++p) {
        const int g0 = 2 * p;
        const int ca = half ? av[g0 + 1] : av[g0];
        const int cb = half ? bv[g0 + 1] : bv[g0];
        const uint4 A = *(const uint4*)(base + (((size_t)(uint32_t)ca) << 9) + lo16);
        const uint4 B = *(const uint4*)(base + (((size_t)(uint32_t)cb) << 9) + lo16);
        const float4 c = coefs[jw + g0 + half];   // 2 distinct addrs per wave

        uint32_t aw[4] = {A.x, A.y, A.z, A.w};
        uint32_t bw[4] = {B.x, B.y, B.z, B.w};
        float r[8];
        #pragma unroll
        for (int i = 0; i < 4; ++i) {
            const float a0 = bfbits(aw[i] & 0xffffu);
            const float a1 = bfbits(aw[i] >> 16);
            const float b0 = bfbits(bw[i] & 0xffffu);
            const float b1 = bfbits(bw[i] >> 16);
            r[2*i]   = fmaf(c.w, a0 * b0, fmaf(c.z, b0, fmaf(c.y, a0, c.x)));
            r[2*i+1] = fmaf(c.w, a1 * b1, fmaf(c.z, b1, fmaf(c.y, a1, c.x)));
        }
        if (FINAL) {
            #pragma unroll
            for (int i = 0; i < 8; ++i) acc[i] += r[i];
        } else {
            uint4 o;
            o.x = f2bf_u(r[0]) | (f2bf_u(r[1]) << 16);
            o.y = f2bf_u(r[2]) | (f2bf_u(r[3]) << 16);
            o.z = f2bf_u(r[4]) | (f2bf_u(r[5]) << 16);
            o.w = f2bf_u(r[6]) | (f2bf_u(r[7]) << 16);
            // gates g0,g0+1 -> contiguous 1 KB across the wave
            *(uint4*)((char*)out + (((size_t)(uint32_t)(jw + g0)) << 9) + (lane << 4)) = o;
        }
    }

    if (FINAL) {
        // fold odd-gate half onto even-gate half (same batch slice per l32)
        #pragma unroll
        for (int i = 0; i < 8; ++i) acc[i] += __shfl_xor(acc[i], 32);
        __shared__ float s[NWAVE][32][8];    // 16 KB
        if (half == 0) {
            #pragma unroll
            for (int i = 0; i < 8; ++i) s[wave][l32][i] = acc[i];
        }
        __syncthreads();
        const int tid = threadIdx.x;
        if (tid < BATCH) {                   // thread t -> batch element t
            const int li = tid >> 3, ii = tid & 7;
            float t = 0.f;
            #pragma unroll
            for (int w = 0; w < NWAVE; ++w) t += s[w][li][ii];
            const int grp = (blockIdx.x * GPB) / GSIZE;
            atomicAdd(&red_out[tid * NGROUP + grp], t * (1.0f / TAU));
        }
    }
}

// ---------------------------------------------------------------- launch
extern "C" void kernel_launch(void* const* d_in, const int* in_sizes, int n_in,
                              void* d_out, int out_size, void* d_ws, size_t ws_size,
                              hipStream_t stream)
{
    const float* x   = (const float*)d_in[0];
    const float* w1  = (const float*)d_in[1];
    const float* w2  = (const float*)d_in[2];
    const float* w3  = (const float*)d_in[3];
    const int*   ia1 = (const int*)d_in[4];
    const int*   ib1 = (const int*)d_in[5];
    const int*   ia2 = (const int*)d_in[6];
    const int*   ib2 = (const int*)d_in[7];
    const int*   ia3 = (const int*)d_in[8];
    const int*   ib3 = (const int*)d_in[9];
    float* out = (float*)d_out;

    // workspace: xT | h1 | h2 | c1 | c2 | c3 (~69 MB, 16B-aligned segments)
    char* ws = (char*)d_ws;
    ushort_t* xT = (ushort_t*)ws;
    ushort_t* h1 = (ushort_t*)(ws + ((size_t)IN_DIM * BATCH * 2));
    ushort_t* h2 = h1 + (size_t)WIDTH * BATCH;
    float*    c1 = (float*)(h2 + (size_t)WIDTH * BATCH);
    float*    c2 = c1 + (size_t)WIDTH * 4;
    float*    c3 = c2 + (size_t)WIDTH * 4;

    hipMemsetAsync(d_out, 0, (size_t)out_size * sizeof(float), stream);

    transpose_kernel<<<64, 256, 0, stream>>>(x, xT);
    coef_kernel<<<(3 * WIDTH) / 256, 256, 0, stream>>>(w1, w2, w3,
                                                       (float4*)c1, (float4*)c2, (float4*)c3);

    logic_layer_kernel<false><<<NBLK, 1024, 0, stream>>>(
        xT, (const float4*)c1, ia1, ib1, h1, nullptr);
    logic_layer_kernel<false><<<NBLK, 1024, 0, stream>>>(
        h1, (const float4*)c2, ia2, ib2, h2, nullptr);
    logic_layer_kernel<true><<<NBLK, 1024, 0, stream>>>(
        h2, (const float4*)c3, ia3, ib3, nullptr, out);
}

// Round 11
// 144.959 us; speedup vs baseline: 1.7933x; 1.0009x over previous
//
#include <hip/hip_runtime.h>
#include <stdint.h>

// DiffLogic: 3-layer differentiable logic network.
// Round 11: LDS-resident network. One workgroup = one batch element.
// h1,h2 live in LDS as fp8 e4m3 (62.5 KB each); x-row fp32 (4 KB).
// All gathers become random LDS byte reads -- zero fabric traffic for h.
// Global traffic = packed metadata only: 12 B/gate {u16 ia,u16 ib,4xbf16},
// streamed coalesced, shared across workgroups via L2.

#define BATCH   256
#define IN_DIM  1024
#define WIDTH   64000
#define NGROUP  10
#define GSIZE   6400
#define TAU     30.0f
#define NTHR    1024

// LDS layout (bytes): xrow fp32 [0,4096) | h1 fp8 [4096,68096) |
//                     h2 fp8 [68096,132096) | gsum f32[16] [132096,132160)
#define LDS_XROW   0
#define LDS_H1     4096
#define LDS_H2     68096
#define LDS_GSUM   132096
#define LDS_BYTES  132160

static __device__ __forceinline__ uint32_t f2bf_u(float f) {   // RNE
    uint32_t u = __float_as_uint(f);
    return (u + 0x7fffu + ((u >> 16) & 1u)) >> 16;
}
static __device__ __forceinline__ float bf_lo(uint32_t u) {
    return __uint_as_float(u << 16);
}
static __device__ __forceinline__ float bf_hi(uint32_t u) {
    return __uint_as_float(u & 0xffff0000u);
}
// fp8 e4m3 (OCP on gfx950) HW converts
static __device__ __forceinline__ uint8_t f2fp8(float f) {
    return (uint8_t)(uint32_t)__builtin_amdgcn_cvt_pk_fp8_f32(f, f, 0, false);
}
static __device__ __forceinline__ float fp82f(uint8_t v) {
    return __builtin_amdgcn_cvt_f32_fp8((int)v, 0);
}

// ---------------------------------------------------------------- pack
// md[layer*WIDTH + j] = {ia | ib<<16, bf16(c0)|bf16(c1)<<16, bf16(c2)|bf16(c3)<<16}
__global__ __launch_bounds__(256) void pack_kernel(
    const float* __restrict__ w1, const float* __restrict__ w2,
    const float* __restrict__ w3,
    const int* __restrict__ ia1, const int* __restrict__ ib1,
    const int* __restrict__ ia2, const int* __restrict__ ib2,
    const int* __restrict__ ia3, const int* __restrict__ ib3,
    uint3* __restrict__ md)
{
    const int id = blockIdx.x * 256 + threadIdx.x;    // 0 .. 191999
    const int layer = id / WIDTH;
    const int j = id - layer * WIDTH;
    const float* w = (layer == 0) ? w1 : (layer == 1) ? w2 : w3;
    const int* ia  = (layer == 0) ? ia1 : (layer == 1) ? ia2 : ia3;
    const int* ib  = (layer == 0) ? ib1 : (layer == 1) ? ib2 : ib3;

    const float4* w4 = (const float4*)(w + (size_t)j * 16);
    float4 q0 = w4[0], q1 = w4[1], q2 = w4[2], q3 = w4[3];
    float p[16] = {q0.x,q0.y,q0.z,q0.w, q1.x,q1.y,q1.z,q1.w,
                   q2.x,q2.y,q2.z,q2.w, q3.x,q3.y,q3.z,q3.w};
    float m = p[0];
    #pragma unroll
    for (int i = 1; i < 16; ++i) m = fmaxf(m, p[i]);
    float s = 0.f;
    #pragma unroll
    for (int i = 0; i < 16; ++i) { p[i] = __expf(p[i] - m); s += p[i]; }
    const float inv = 1.0f / s;

    float c0 = (p[8]+p[9]+p[10]+p[11]+p[12]+p[13]+p[14]+p[15]) * inv;
    float c1 = (p[2]+p[3]+p[6]+p[7] - p[8]-p[9]-p[12]-p[13]) * inv;
    float c2 = (p[4]+p[5]+p[6]+p[7] - p[8]-p[9]-p[10]-p[11]) * inv;
    float c3 = (p[1]-p[2]-p[4]-2.f*p[6]-p[7]+p[8]+2.f*p[9]+p[11]+p[13]-p[14]) * inv;

    uint3 o;
    o.x = (uint32_t)ia[j] | ((uint32_t)ib[j] << 16);
    o.y = f2bf_u(c0) | (f2bf_u(c1) << 16);
    o.z = f2bf_u(c2) | (f2bf_u(c3) << 16);
    md[id] = o;
}

// ---------------------------------------------------------------- fused net
__global__ __launch_bounds__(NTHR) void fused_kernel(
    const float* __restrict__ x,
    const uint3* __restrict__ md,
    float* __restrict__ out)
{
    extern __shared__ char lds[];
    float*   xrow = (float*)(lds + LDS_XROW);
    uint8_t* h1   = (uint8_t*)(lds + LDS_H1);
    uint8_t* h2   = (uint8_t*)(lds + LDS_H2);
    float*   gsum = (float*)(lds + LDS_GSUM);

    const int tid = threadIdx.x;
    const int b   = blockIdx.x;           // batch element

    xrow[tid] = x[b * IN_DIM + tid];      // IN_DIM == NTHR, coalesced
    if (tid < NGROUP) gsum[tid] = 0.f;
    __syncthreads();

    // ---- layer 1: x (fp32 LDS) -> h1 (fp8 LDS) ----
    {
        const uint3* m1 = md;
        for (int k = 0; k < 63; ++k) {
            const int j = tid + (k << 10);
            if (j < WIDTH) {
                const uint3 m = m1[j];
                const float a  = xrow[m.x & 0xffffu];
                const float bb = xrow[m.x >> 16];
                const float r = fmaf(bf_hi(m.z), a * bb,
                                fmaf(bf_lo(m.z), bb,
                                fmaf(bf_hi(m.y), a, bf_lo(m.y))));
                h1[j] = f2fp8(r);
            }
        }
    }
    __syncthreads();

    // ---- layer 2: h1 -> h2 ----
    {
        const uint3* m2 = md + WIDTH;
        for (int k = 0; k < 63; ++k) {
            const int j = tid + (k << 10);
            if (j < WIDTH) {
                const uint3 m = m2[j];
                const float a  = fp82f(h1[m.x & 0xffffu]);
                const float bb = fp82f(h1[m.x >> 16]);
                const float r = fmaf(bf_hi(m.z), a * bb,
                                fmaf(bf_lo(m.z), bb,
                                fmaf(bf_hi(m.y), a, bf_lo(m.y))));
                h2[j] = f2fp8(r);
            }
        }
    }
    __syncthreads();

    // ---- layer 3: h2 -> grouped sums ----
    {
        const uint3* m3 = md + 2 * WIDTH;
        float acc = 0.f;
        int curg = tid / GSIZE;           // group of j at k=0
        for (int k = 0; k < 63; ++k) {
            const int j = tid + (k << 10);
            if (j < WIDTH) {
                const int g = j / GSIZE;  // monotone in k
                if (g != curg) { atomicAdd(&gsum[curg], acc); acc = 0.f; curg = g; }
                const uint3 m = m3[j];
                const float a  = fp82f(h2[m.x & 0xffffu]);
                const float bb = fp82f(h2[m.x >> 16]);
                acc += fmaf(bf_hi(m.z), a * bb,
                       fmaf(bf_lo(m.z), bb,
                       fmaf(bf_hi(m.y), a, bf_lo(m.y))));
            }
        }
        atomicAdd(&gsum[curg], acc);
    }
    __syncthreads();

    if (tid < NGROUP) out[b * NGROUP + tid] = gsum[tid] * (1.0f / TAU);
}

// ---------------------------------------------------------------- launch
extern "C" void kernel_launch(void* const* d_in, const int* in_sizes, int n_in,
                              void* d_out, int out_size, void* d_ws, size_t ws_size,
                              hipStream_t stream)
{
    const float* x   = (const float*)d_in[0];
    const float* w1  = (const float*)d_in[1];
    const float* w2  = (const float*)d_in[2];
    const float* w3  = (const float*)d_in[3];
    const int*   ia1 = (const int*)d_in[4];
    const int*   ib1 = (const int*)d_in[5];
    const int*   ia2 = (const int*)d_in[6];
    const int*   ib2 = (const int*)d_in[7];
    const int*   ia3 = (const int*)d_in[8];
    const int*   ib3 = (const int*)d_in[9];
    float* out = (float*)d_out;

    uint3* md = (uint3*)d_ws;             // 192000 * 12 B = 2.25 MB

    // allow >64 KB dynamic LDS (gfx950: 160 KiB/WG GROUP segment)
    hipFuncSetAttribute((const void*)fused_kernel,
                        hipFuncAttributeMaxDynamicSharedMemorySize, LDS_BYTES);

    pack_kernel<<<(3 * WIDTH) / 256, 256, 0, stream>>>(
        w1, w2, w3, ia1, ib1, ia2, ib2, ia3, ib3, md);

    fused_kernel<<<BATCH, NTHR, LDS_BYTES, stream>>>(x, md, out);
}